// Round 6
// baseline (461.217 us; speedup 1.0000x reference)
//
#include <hip/hip_runtime.h>
#include <cstdint>
#include <cstddef>

#define T_SEQ 512
#define BATCH 64
#define IN_SZ 512
#define HID   1024
#define BH    (BATCH*HID)      /* 65536 */
#define M_TOT (T_SEQ*BATCH)    /* 32768 */
#define D_CH  16               /* scan chunk depth */

typedef float f32x4 __attribute__((ext_vector_type(4)));
typedef _Float16 f16x8 __attribute__((ext_vector_type(8)));

__device__ inline unsigned short f2h(float f){
  union { _Float16 h; unsigned short u; } v;
  v.h = (_Float16)f;            // RTNE
  return v.u;
}
__device__ inline float h2f(unsigned short s){
  union { unsigned short u; _Float16 h; } v; v.u = s;
  return (float)v.h;
}

__device__ inline float sigm_f(float x){ return 1.f/(1.f + __expf(-x)); }
__device__ inline float tanh_f(float x){ float e = __expf(2.f*x); return 1.f - 2.f/(e + 1.f); }

// async global->LDS, 16B per lane; lds base must be wave-uniform
__device__ inline void async16(const void* g, void* l){
  __builtin_amdgcn_global_load_lds(
      (__attribute__((address_space(1))) void*)g,
      (__attribute__((address_space(3))) void*)l,
      16, 0, 0);
}

// ---------- fp32 -> fp16 conversion for U matrices ONLY (9 MB total) ----------
// x-conversion is now fused into gemm3's A staging (reg-staged fp32->fp16).
__global__ __launch_bounds__(256) void cvt_all(
    const float* __restrict__ Uc, const float* __restrict__ Ua, const float* __restrict__ Uh,
    unsigned short* __restrict__ U0, unsigned short* __restrict__ U1,
    unsigned short* __restrict__ U2)
{
  int b = blockIdx.x;              // 0..1535
  int which = b >> 9;              // 0..2
  int lb = b & 511;
  int i = lb*256 + threadIdx.x;
  const float* in  = (which==0) ? Uc : (which==1) ? Ua : Uh;
  unsigned short* out = (which==0) ? U0 : (which==1) ? U1 : U2;
  float4 v = ((const float4*)in)[i];
  ushort4 o;
  o.x = f2h(v.x); o.y = f2h(v.y); o.z = f2h(v.z); o.w = f2h(v.w);
  ((ushort4*)out)[i] = o;
}

// ---------- fused 3-projection GEMM: 256x256 tile, BK=64, 8 waves, phase-interleaved ----
// Same verified r2 schedule/LDS image; A is now reg-staged from fp32 x:
//   issue 4 global_load_dwordx4 (3 phases ahead) -> cvt fp16 -> 1 ds_write_b128/chunk,
//   identical cg8 source swizzle + linear LDS dest => ds-read/MFMA side untouched.
// B stays on global_load_lds. vmcnt ledger (conservative min over issue orderings):
//   steady p2/p4 = vmcnt(6); tail p4(5)=2, p2(6)=4, p4(6)=2, p2(7)=0.
// ds_writes published via pre-barrier lgkmcnt(0) + sched_barrier(0) (rule #18);
// slot overwrite at p2/p4 is safe: the overwritten half was last read in the
// immediately preceding phase, separated by that phase's trailing barrier.
__global__ __launch_bounds__(512, 2) void gemm3(
    const float* __restrict__ xf,
    const unsigned short* __restrict__ U0,
    const unsigned short* __restrict__ U1,
    const unsigned short* __restrict__ U2,
    const float* __restrict__ b0, const float* __restrict__ b1, const float* __restrict__ b2,
    unsigned short* out0, unsigned short* out1, void* out2, int ph_f16)
{
  __shared__ __align__(16) unsigned char smem_raw[131072];

  const int tid  = threadIdx.x;
  const int wave = tid >> 6, lane = tid & 63;
  const int quad = lane >> 4, l16 = lane & 15;

  const int bid  = blockIdx.x;          // 0..1535
  const int xcd  = bid & 7;
  const int slot = bid >> 3;            // 0..191
  const int mbl  = slot / 12;           // 0..15
  const int inner= slot - mbl*12;       // 0..11
  const int mb   = xcd*16 + mbl;        // 0..127
  const int z    = inner % 3;
  const int nb   = inner / 3;           // 0..3

  const int m0 = mb * 256, n0 = nb * 256;
  const unsigned short* Um = (z==0) ? U0 : (z==1) ? U1 : U2;
  const float* bias        = (z==0) ? b0 : (z==1) ? b1 : b2;
  const int wm = wave >> 2, wn = wave & 3;   // 2 x 4 wave grid; per-wave 128x64

  const int laneRow = lane >> 2;
  const int cg8     = ((lane & 3) ^ ((lane >> 3) & 3)) << 3;   // element offset (8-elem chunks)
  const unsigned short* srcB = Um + (size_t)n0 * IN_SZ;

  const int cxa = l16*64 + ((quad ^ ((l16 >> 1) & 3)) << 4);

  // --- A path: fp32 loads -> regs -> fp16 ds_write (LDS image identical to r2) ---
  auto issueA = [&](int tile, int kh, float4* ar){
#pragma unroll
    for (int j = 0; j < 2; ++j){
      const int row = (wave*2 + j)*16 + laneRow;
      const float* g = xf + (size_t)(m0 + row)*IN_SZ + tile*64 + kh*32 + cg8;
      ar[2*j]   = *(const float4*)(g);
      ar[2*j+1] = *(const float4*)(g + 4);
    }
  };
  auto writeA = [&](int tile, int kh, const float4* ar){
    unsigned char* dst = smem_raw + (((tile & 1)*2 + kh) << 14);
#pragma unroll
    for (int j = 0; j < 2; ++j){
      f16x8 v;
      v[0] = (_Float16)ar[2*j].x;   v[1] = (_Float16)ar[2*j].y;
      v[2] = (_Float16)ar[2*j].z;   v[3] = (_Float16)ar[2*j].w;
      v[4] = (_Float16)ar[2*j+1].x; v[5] = (_Float16)ar[2*j+1].y;
      v[6] = (_Float16)ar[2*j+1].z; v[7] = (_Float16)ar[2*j+1].w;
      *(f16x8*)(dst + (wave*2 + j)*1024 + lane*16) = v;
    }
  };
  auto stageB = [&](int tile, int kh){
    unsigned char* dst = smem_raw + 65536 + (((tile & 1)*2 + kh) << 14);
#pragma unroll
    for (int j = 0; j < 2; ++j){
      const unsigned short* g = srcB + (size_t)((wave*2 + j)*16 + laneRow)*IN_SZ
                                + tile*64 + kh*32 + cg8;
      async16(g, dst + (wave*2 + j)*1024);
    }
  };

  const f32x4 zf = {0.f, 0.f, 0.f, 0.f};
  f32x4 acc[8][4];
#pragma unroll
  for (int i = 0; i < 8; ++i)
#pragma unroll
    for (int j = 0; j < 4; ++j) acc[i][j] = zf;

  // ---- prologue: two drain stages (one-time cost; keeps VGPR peak modest) ----
  float4 ar0[4], ar1[4];
  {
    float4 aP0[4], aP1[4];
    issueA(0,0,aP0); issueA(0,1,aP1);
    asm volatile("s_waitcnt vmcnt(0)" ::: "memory");
    writeA(0,0,aP0); writeA(0,1,aP1);
    issueA(1,0,aP0); issueA(1,1,aP1);
    stageB(0,0); stageB(0,1); stageB(1,0);
    issueA(2,0,ar0);                      // consumed at p2(0)
    asm volatile("s_waitcnt vmcnt(0)" ::: "memory");
    writeA(1,0,aP0); writeA(1,1,aP1);
    asm volatile("s_waitcnt lgkmcnt(0)" ::: "memory");
    __builtin_amdgcn_sched_barrier(0);
    __builtin_amdgcn_s_barrier();
  }

#define CLUSTER(B0_, B1_, N0_, N1_)                                                      \
  __builtin_amdgcn_s_barrier();                                                          \
  asm volatile("s_waitcnt lgkmcnt(0)" ::: "memory");                                     \
  __builtin_amdgcn_s_setprio(1);                                                         \
  _Pragma("unroll")                                                                      \
  for (int im_ = 0; im_ < 8; ++im_){                                                     \
    acc[im_][N0_] = __builtin_amdgcn_mfma_f32_16x16x32_f16(a0[im_], B0_, acc[im_][N0_], 0,0,0); \
    acc[im_][N1_] = __builtin_amdgcn_mfma_f32_16x16x32_f16(a0[im_], B1_, acc[im_][N1_], 0,0,0); \
  }                                                                                      \
  __builtin_amdgcn_s_setprio(0);                                                         \
  __builtin_amdgcn_s_barrier();

  f16x8 a0[8];
#pragma unroll
  for (int g = 0; g < 8; ++g){
    const int buf = g & 1;
    const unsigned char* Ab0 = smem_raw + ((buf*2 + 0) << 14);
    const unsigned char* Ab1 = smem_raw + ((buf*2 + 1) << 14);
    const unsigned char* Bb0 = smem_raw + 65536 + ((buf*2 + 0) << 14);
    const unsigned char* Bb1 = smem_raw + 65536 + ((buf*2 + 1) << 14);

    // ---- p1: ks0, n-frags 0,1 | issue A(g+2,1) loads, stage B(g+1,1)
#pragma unroll
    for (int im = 0; im < 8; ++im)
      a0[im] = *(const f16x8*)(Ab0 + wm*8192 + im*1024 + cxa);
    f16x8 q0 = *(const f16x8*)(Bb0 + wn*4096 + 0*1024 + cxa);
    f16x8 q1 = *(const f16x8*)(Bb0 + wn*4096 + 1*1024 + cxa);
    if (g < 6) issueA(g+2, 1, ar1);
    if (g < 7) stageB(g+1, 1);
    CLUSTER(q0, q1, 0, 1)

    // ---- p2: ks0, n-frags 2,3 | write A(g+2,0)
    f16x8 q2 = *(const f16x8*)(Bb0 + wn*4096 + 2*1024 + cxa);
    f16x8 q3 = *(const f16x8*)(Bb0 + wn*4096 + 3*1024 + cxa);
    if (g < 6)      { asm volatile("s_waitcnt vmcnt(6)" ::: "memory"); }
    else if (g == 6){ asm volatile("s_waitcnt vmcnt(4)" ::: "memory"); }
    else            { asm volatile("s_waitcnt vmcnt(0)" ::: "memory"); }
    if (g < 6) writeA(g+2, 0, ar0);
    asm volatile("s_waitcnt lgkmcnt(0)" ::: "memory");
    __builtin_amdgcn_sched_barrier(0);
    CLUSTER(q2, q3, 2, 3)

    // ---- p3: ks1, n-frags 0,1 | issue A(g+3,0) loads, stage B(g+2,0)
#pragma unroll
    for (int im = 0; im < 8; ++im)
      a0[im] = *(const f16x8*)(Ab1 + wm*8192 + im*1024 + cxa);
    q0 = *(const f16x8*)(Bb1 + wn*4096 + 0*1024 + cxa);
    q1 = *(const f16x8*)(Bb1 + wn*4096 + 1*1024 + cxa);
    if (g < 5) issueA(g+3, 0, ar0);
    if (g < 6) stageB(g+2, 0);
    CLUSTER(q0, q1, 0, 1)

    // ---- p4: ks1, n-frags 2,3 | write A(g+2,1)
    q2 = *(const f16x8*)(Bb1 + wn*4096 + 2*1024 + cxa);
    q3 = *(const f16x8*)(Bb1 + wn*4096 + 3*1024 + cxa);
    if (g < 5)      { asm volatile("s_waitcnt vmcnt(6)" ::: "memory"); }
    else if (g == 5){ asm volatile("s_waitcnt vmcnt(2)" ::: "memory"); }
    else if (g == 6){ asm volatile("s_waitcnt vmcnt(2)" ::: "memory"); }
    if (g < 6) writeA(g+2, 1, ar1);
    asm volatile("s_waitcnt lgkmcnt(0)" ::: "memory");
    __builtin_amdgcn_sched_barrier(0);
    CLUSTER(q2, q3, 2, 3)
  }
#undef CLUSTER

  float bv[4];
#pragma unroll
  for (int in = 0; in < 4; ++in) bv[in] = bias[n0 + wn*64 + in*16 + l16];

  if (z == 2 && !ph_f16) {
    float* o32 = (float*)out2;
#pragma unroll
    for (int im = 0; im < 8; ++im)
#pragma unroll
      for (int r = 0; r < 4; ++r){
        int grow = m0 + wm*128 + im*16 + quad*4 + r;
        size_t rb = (size_t)grow * HID;
#pragma unroll
        for (int in = 0; in < 4; ++in)
          o32[rb + n0 + wn*64 + in*16 + l16] = acc[im][in][r] + bv[in];
      }
    return;
  }

  unsigned short* op = (z==0) ? out0 : (z==1) ? out1 : (unsigned short*)out2;
  unsigned short* sw = (unsigned short*)smem_raw + wave*4608;
#pragma unroll
  for (int h = 0; h < 2; ++h){
#pragma unroll
    for (int i4 = 0; i4 < 4; ++i4){
      int im = h*4 + i4;
#pragma unroll
      for (int r = 0; r < 4; ++r){
        int lr = i4*16 + quad*4 + r;
#pragma unroll
        for (int in = 0; in < 4; ++in)
          sw[lr*72 + in*16 + l16] = f2h(acc[im][in][r] + bv[in]);
      }
    }
    asm volatile("s_waitcnt lgkmcnt(0)" ::: "memory");
#pragma unroll
    for (int i = 0; i < 8; ++i){
      int lr = i*8 + (lane >> 3);
      int ch = lane & 7;
      uint4 v = *(const uint4*)(sw + lr*72 + ch*8);
      int grow = m0 + wm*128 + h*64 + lr;
      *(uint4*)(op + (size_t)grow*HID + n0 + wn*64 + ch*8) = v;
    }
    if (h == 0) asm volatile("s_waitcnt lgkmcnt(0)" ::: "memory");
  }
}

// ---------- elementwise recurrence, v2: block-cooperative LDS staging ----------
// (byte-identical to verified round-2 version)
template <bool PH16>
__global__ __launch_bounds__(256) void scan_k(
    const unsigned short* __restrict__ pc, const unsigned short* __restrict__ pa,
    const void* __restrict__ phv,
    float* __restrict__ y,
    const float* __restrict__ h0, const float* __restrict__ wc, const float* __restrict__ wa,
    float* __restrict__ hlast)
{
  __shared__ __align__(16) unsigned char sm[65536];
  const int tid  = threadIdx.x;
  const int wave = tid >> 6, lane = tid & 63;
  const int col0 = blockIdx.x * 256;
  const int idx  = col0 + tid;
  const int hidx = idx & (HID - 1);

  float h = h0[idx];
  const float wcv = wc[hidx], wav = wa[hidx];
  const unsigned short* ph16 = (const unsigned short*)phv;
  const float*          ph32 = (const float*)phv;

  unsigned char* pcL = sm;
  unsigned char* paL = sm + 16384;
  unsigned char* phL = sm + 32768;

  auto stage = [&](int c){
    const int b  = c & 1;
    const int t0 = c * D_CH;
#pragma unroll
    for (int j = 0; j < 2; ++j){
      const int tr  = wave*2 + j*8;
      const int row = tr + (lane >> 5);
      const int ce  = (lane & 31) * 8;
      async16(pc + (size_t)(t0+row)*BH + col0 + ce, pcL + b*8192 + tr*512);
      async16(pa + (size_t)(t0+row)*BH + col0 + ce, paL + b*8192 + tr*512);
    }
    if (PH16){
#pragma unroll
      for (int j = 0; j < 2; ++j){
        const int tr  = wave*2 + j*8;
        const int row = tr + (lane >> 5);
        const int ce  = (lane & 31) * 8;
        async16(ph16 + (size_t)(t0+row)*BH + col0 + ce, phL + b*8192 + tr*512);
      }
    } else {
#pragma unroll
      for (int j = 0; j < 4; ++j){
        const int t = wave + j*4;
        async16(ph32 + (size_t)(t0+t)*BH + col0 + lane*4, phL + b*16384 + t*1024);
      }
    }
  };

  stage(0);
  asm volatile("s_waitcnt vmcnt(0)" ::: "memory");
  __builtin_amdgcn_s_barrier();
  __builtin_amdgcn_sched_barrier(0);

  constexpr int NC = T_SEQ / D_CH;
  for (int c = 0; c < NC; ++c){
    if (c + 1 < NC) stage(c + 1);
    const int b  = c & 1;
    const int t0 = c * D_CH;
    const unsigned short* pcb   = (const unsigned short*)(pcL + b*8192)  + tid;
    const unsigned short* pab   = (const unsigned short*)(paL + b*8192)  + tid;
    const unsigned short* phb16 = (const unsigned short*)(phL + b*8192)  + tid;
    const float*          phb32 = (const float*)(phL + b*16384) + tid;
#pragma unroll
    for (int i = 0; i < D_CH; ++i){
      float pcv = h2f(pcb[i*256]);
      float pav = h2f(pab[i*256]);
      float ph_ = PH16 ? h2f(phb16[i*256]) : phb32[i*256];
      float cc = sigm_f(pcv + wcv*h);
      float a  = 1.f + tanh_f(pav + wav*h);
      float hc = tanh_f(ph_ + a*h);
      h = cc*h + (1.f - cc)*hc;
      y[(size_t)(t0 + i)*BH + idx] = h;
    }
    if (c + 1 < NC){
      asm volatile("s_waitcnt vmcnt(16)" ::: "memory");
      __builtin_amdgcn_s_barrier();
      __builtin_amdgcn_sched_barrier(0);
    }
  }
  hlast[idx] = h;
}

extern "C" void kernel_launch(void* const* d_in, const int* in_sizes, int n_in,
                              void* d_out, int out_size, void* d_ws, size_t ws_size,
                              hipStream_t stream)
{
  const float* x  = (const float*)d_in[0];
  const float* h0 = (const float*)d_in[1];
  const float* Uc = (const float*)d_in[2];
  const float* wc = (const float*)d_in[3];
  const float* bc = (const float*)d_in[4];
  const float* Ua = (const float*)d_in[5];
  const float* wa = (const float*)d_in[6];
  const float* ba = (const float*)d_in[7];
  const float* Uh = (const float*)d_in[8];
  const float* bh = (const float*)d_in[9];

  float* y     = (float*)d_out;                 // [T,B,H]
  float* hlast = y + (size_t)T_SEQ * BH;        // [B,H]

  const size_t szP16 = (size_t)T_SEQ * BH * 2;     // 67,108,864 B
  const size_t szX16 = (size_t)M_TOT * IN_SZ * 2;  // 33,554,432 B (xb slot now unused)
  const size_t szU16 = (size_t)HID * IN_SZ * 2;    // 1,048,576 B

  const size_t base = 2*szP16 + szX16 + 3*szU16;
  const bool ph_sep = ws_size >= base + szP16;     // separate fp16 ph buffer?

  char* w = (char*)d_ws;
  unsigned short* pc16 = (unsigned short*)w;
  unsigned short* pa16 = (unsigned short*)(w + szP16);
  unsigned short* U0b  = (unsigned short*)(w + 2*szP16 + szX16);
  unsigned short* U1b  = U0b + szU16/2;
  unsigned short* U2b  = U1b + szU16/2;
  unsigned short* ph16 = (unsigned short*)(w + base);   // only if ph_sep

  cvt_all<<<1536, 256, 0, stream>>>(Uc, Ua, Uh, U0b, U1b, U2b);

  void* phbuf = ph_sep ? (void*)ph16 : (void*)y;
  gemm3<<<1536, 512, 0, stream>>>(x, U0b, U1b, U2b, bc, ba, bh,
                                  pc16, pa16, phbuf, ph_sep ? 1 : 0);

  if (ph_sep)
    scan_k<true><<<BH/256, 256, 0, stream>>>(pc16, pa16, (const void*)ph16,
                                             y, h0, wc, wa, hlast);
  else
    scan_k<false><<<BH/256, 256, 0, stream>>>(pc16, pa16, (const void*)y,
                                              y, h0, wc, wa, hlast);
}

// Round 7
// 400.924 us; speedup vs baseline: 1.1504x; 1.1504x over previous
//
#include <hip/hip_runtime.h>
#include <cstdint>
#include <cstddef>

#define T_SEQ 512
#define BATCH 64
#define IN_SZ 512
#define HID   1024
#define BH    (BATCH*HID)      /* 65536 */
#define M_TOT (T_SEQ*BATCH)    /* 32768 */
#define D_CH  16               /* scan chunk depth */

typedef float f32x4 __attribute__((ext_vector_type(4)));
typedef _Float16 f16x8 __attribute__((ext_vector_type(8)));

__device__ inline unsigned short f2h(float f){
  union { _Float16 h; unsigned short u; } v;
  v.h = (_Float16)f;            // RTNE
  return v.u;
}
__device__ inline float h2f(unsigned short s){
  union { unsigned short u; _Float16 h; } v; v.u = s;
  return (float)v.h;
}

__device__ inline float sigm_f(float x){ return 1.f/(1.f + __expf(-x)); }
__device__ inline float tanh_f(float x){ float e = __expf(2.f*x); return 1.f - 2.f/(e + 1.f); }

// async global->LDS, 16B per lane; lds base must be wave-uniform
__device__ inline void async16(const void* g, void* l){
  __builtin_amdgcn_global_load_lds(
      (__attribute__((address_space(1))) void*)g,
      (__attribute__((address_space(3))) void*)l,
      16, 0, 0);
}

// ---------- fused fp32 -> fp16 conversion for x, Uc, Ua, Uh ----------
// (byte-identical to verified round-2 version)
#define XBLK 16384
__global__ __launch_bounds__(256) void cvt_all(
    const float* __restrict__ x,  const float* __restrict__ Uc,
    const float* __restrict__ Ua, const float* __restrict__ Uh,
    unsigned short* __restrict__ xb, unsigned short* __restrict__ U0,
    unsigned short* __restrict__ U1, unsigned short* __restrict__ U2)
{
  int b = blockIdx.x;
  const float* in; unsigned short* out; int i;
  if (b < XBLK){
    in = x; out = xb; i = b*256 + threadIdx.x;
  } else {
    int r = b - XBLK;
    int which = r >> 9;            // 0..2
    int lb = r & 511;
    i = lb*256 + threadIdx.x;
    in  = (which==0) ? Uc : (which==1) ? Ua : Uh;
    out = (which==0) ? U0 : (which==1) ? U1 : U2;
  }
  float4 v = ((const float4*)in)[i];
  ushort4 o;
  o.x = f2h(v.x); o.y = f2h(v.y); o.z = f2h(v.z); o.w = f2h(v.w);
  ((ushort4*)out)[i] = o;
}

// ---------- single-projection GEMM: 256x256 tile, BK=64, 8 waves ----------
// Internals byte-identical to the verified r2 schedule; the z dimension is now a
// LAUNCH dimension (3 launches of 512 blocks) so each dispatch is ~45us — this
// drops gemm below scan/cvt durations and forces them into rocprof's top-5
// (observability), and gives 2 clean occupancy rounds per CU (512 = 2x256).
// Grid 512 = 8 xcd * 16 mb * 4 nb; consecutive same-XCD slots share one A panel.
__global__ __launch_bounds__(512, 2) void gemm3(
    const unsigned short* __restrict__ xb,
    const unsigned short* __restrict__ Um,
    const float* __restrict__ bias,
    void* outp, int ph32_mode)
{
  __shared__ __align__(16) unsigned char smem_raw[131072];

  const int tid  = threadIdx.x;
  const int wave = tid >> 6, lane = tid & 63;
  const int quad = lane >> 4, l16 = lane & 15;

  const int bid  = blockIdx.x;          // 0..511
  const int xcd  = bid & 7;
  const int slot = bid >> 3;            // 0..63
  const int mbl  = slot >> 2;           // 0..15
  const int nb   = slot & 3;            // 0..3
  const int mb   = xcd*16 + mbl;        // 0..127

  const int m0 = mb * 256, n0 = nb * 256;
  const int wm = wave >> 2, wn = wave & 3;   // 2 x 4 wave grid; per-wave 128x64

  const int laneRow = lane >> 2;
  const int cg8     = ((lane & 3) ^ ((lane >> 3) & 3)) << 3;
  const unsigned short* srcA = xb + (size_t)m0 * IN_SZ;
  const unsigned short* srcB = Um + (size_t)n0 * IN_SZ;

  const int cxa = l16*64 + ((quad ^ ((l16 >> 1) & 3)) << 4);

  auto stageA = [&](int tile, int kh){
    unsigned char* dst = smem_raw + (((tile & 1)*2 + kh) << 14);
#pragma unroll
    for (int j = 0; j < 2; ++j){
      const unsigned short* g = srcA + (size_t)((wave*2 + j)*16 + laneRow)*IN_SZ
                                + tile*64 + kh*32 + cg8;
      async16(g, dst + (wave*2 + j)*1024);
    }
  };
  auto stageB = [&](int tile, int kh){
    unsigned char* dst = smem_raw + 65536 + (((tile & 1)*2 + kh) << 14);
#pragma unroll
    for (int j = 0; j < 2; ++j){
      const unsigned short* g = srcB + (size_t)((wave*2 + j)*16 + laneRow)*IN_SZ
                                + tile*64 + kh*32 + cg8;
      async16(g, dst + (wave*2 + j)*1024);
    }
  };

  const f32x4 zf = {0.f, 0.f, 0.f, 0.f};
  f32x4 acc[8][4];
#pragma unroll
  for (int i = 0; i < 8; ++i)
#pragma unroll
    for (int j = 0; j < 4; ++j) acc[i][j] = zf;

  stageA(0,0); stageB(0,0); stageA(0,1); stageB(0,1);
  stageA(1,0); stageB(1,0); stageA(1,1);
  asm volatile("s_waitcnt vmcnt(10)" ::: "memory");
  __builtin_amdgcn_s_barrier();

#define CLUSTER(B0_, B1_, N0_, N1_)                                                      \
  __builtin_amdgcn_s_barrier();                                                          \
  asm volatile("s_waitcnt lgkmcnt(0)" ::: "memory");                                     \
  __builtin_amdgcn_s_setprio(1);                                                         \
  _Pragma("unroll")                                                                      \
  for (int im_ = 0; im_ < 8; ++im_){                                                     \
    acc[im_][N0_] = __builtin_amdgcn_mfma_f32_16x16x32_f16(a0[im_], B0_, acc[im_][N0_], 0,0,0); \
    acc[im_][N1_] = __builtin_amdgcn_mfma_f32_16x16x32_f16(a0[im_], B1_, acc[im_][N1_], 0,0,0); \
  }                                                                                      \
  __builtin_amdgcn_s_setprio(0);                                                         \
  __builtin_amdgcn_s_barrier();

  f16x8 a0[8];
#pragma unroll
  for (int g = 0; g < 8; ++g){
    const int buf = g & 1;
    const unsigned char* Ab0 = smem_raw + ((buf*2 + 0) << 14);
    const unsigned char* Ab1 = smem_raw + ((buf*2 + 1) << 14);
    const unsigned char* Bb0 = smem_raw + 65536 + ((buf*2 + 0) << 14);
    const unsigned char* Bb1 = smem_raw + 65536 + ((buf*2 + 1) << 14);

    // ---- p1: ks0, n-frags 0,1
#pragma unroll
    for (int im = 0; im < 8; ++im)
      a0[im] = *(const f16x8*)(Ab0 + wm*8192 + im*1024 + cxa);
    f16x8 q0 = *(const f16x8*)(Bb0 + wn*4096 + 0*1024 + cxa);
    f16x8 q1 = *(const f16x8*)(Bb0 + wn*4096 + 1*1024 + cxa);
    if (g < 7) stageB(g+1, 1);
    CLUSTER(q0, q1, 0, 1)

    // ---- p2: ks0, n-frags 2,3
    f16x8 q2 = *(const f16x8*)(Bb0 + wn*4096 + 2*1024 + cxa);
    f16x8 q3 = *(const f16x8*)(Bb0 + wn*4096 + 3*1024 + cxa);
    if (g < 6) stageA(g+2, 0);
    if (g < 6)      { asm volatile("s_waitcnt vmcnt(10)" ::: "memory"); }
    else if (g == 6){ asm volatile("s_waitcnt vmcnt(8)"  ::: "memory"); }
    else            { asm volatile("s_waitcnt vmcnt(0)"  ::: "memory"); }
    CLUSTER(q2, q3, 2, 3)

    // ---- p3: ks1, n-frags 0,1
#pragma unroll
    for (int im = 0; im < 8; ++im)
      a0[im] = *(const f16x8*)(Ab1 + wm*8192 + im*1024 + cxa);
    q0 = *(const f16x8*)(Bb1 + wn*4096 + 0*1024 + cxa);
    q1 = *(const f16x8*)(Bb1 + wn*4096 + 1*1024 + cxa);
    if (g < 6) stageB(g+2, 0);
    CLUSTER(q0, q1, 0, 1)

    // ---- p4: ks1, n-frags 2,3
    q2 = *(const f16x8*)(Bb1 + wn*4096 + 2*1024 + cxa);
    q3 = *(const f16x8*)(Bb1 + wn*4096 + 3*1024 + cxa);
    if (g < 6) stageA(g+2, 1);
    if (g < 6)      { asm volatile("s_waitcnt vmcnt(10)" ::: "memory"); }
    else if (g == 6){ asm volatile("s_waitcnt vmcnt(4)"  ::: "memory"); }
    CLUSTER(q2, q3, 2, 3)
  }
#undef CLUSTER

  float bv[4];
#pragma unroll
  for (int in = 0; in < 4; ++in) bv[in] = bias[n0 + wn*64 + in*16 + l16];

  if (ph32_mode) {
    float* o32 = (float*)outp;
#pragma unroll
    for (int im = 0; im < 8; ++im)
#pragma unroll
      for (int r = 0; r < 4; ++r){
        int grow = m0 + wm*128 + im*16 + quad*4 + r;
        size_t rb = (size_t)grow * HID;
#pragma unroll
        for (int in = 0; in < 4; ++in)
          o32[rb + n0 + wn*64 + in*16 + l16] = acc[im][in][r] + bv[in];
      }
    return;
  }

  unsigned short* op = (unsigned short*)outp;
  unsigned short* sw = (unsigned short*)smem_raw + wave*4608;
#pragma unroll
  for (int h = 0; h < 2; ++h){
#pragma unroll
    for (int i4 = 0; i4 < 4; ++i4){
      int im = h*4 + i4;
#pragma unroll
      for (int r = 0; r < 4; ++r){
        int lr = i4*16 + quad*4 + r;
#pragma unroll
        for (int in = 0; in < 4; ++in)
          sw[lr*72 + in*16 + l16] = f2h(acc[im][in][r] + bv[in]);
      }
    }
    asm volatile("s_waitcnt lgkmcnt(0)" ::: "memory");
#pragma unroll
    for (int i = 0; i < 8; ++i){
      int lr = i*8 + (lane >> 3);
      int ch = lane & 7;
      uint4 v = *(const uint4*)(sw + lr*72 + ch*8);
      int grow = m0 + wm*128 + h*64 + lr;
      *(uint4*)(op + (size_t)grow*HID + n0 + wn*64 + ch*8) = v;
    }
    if (h == 0) asm volatile("s_waitcnt lgkmcnt(0)" ::: "memory");
  }
}

// ---------- elementwise recurrence, v2: block-cooperative LDS staging ----------
// (byte-identical to verified round-2 version)
template <bool PH16>
__global__ __launch_bounds__(256) void scan_k(
    const unsigned short* __restrict__ pc, const unsigned short* __restrict__ pa,
    const void* __restrict__ phv,
    float* __restrict__ y,
    const float* __restrict__ h0, const float* __restrict__ wc, const float* __restrict__ wa,
    float* __restrict__ hlast)
{
  __shared__ __align__(16) unsigned char sm[65536];
  const int tid  = threadIdx.x;
  const int wave = tid >> 6, lane = tid & 63;
  const int col0 = blockIdx.x * 256;
  const int idx  = col0 + tid;
  const int hidx = idx & (HID - 1);

  float h = h0[idx];
  const float wcv = wc[hidx], wav = wa[hidx];
  const unsigned short* ph16 = (const unsigned short*)phv;
  const float*          ph32 = (const float*)phv;

  unsigned char* pcL = sm;
  unsigned char* paL = sm + 16384;
  unsigned char* phL = sm + 32768;

  auto stage = [&](int c){
    const int b  = c & 1;
    const int t0 = c * D_CH;
#pragma unroll
    for (int j = 0; j < 2; ++j){
      const int tr  = wave*2 + j*8;
      const int row = tr + (lane >> 5);
      const int ce  = (lane & 31) * 8;
      async16(pc + (size_t)(t0+row)*BH + col0 + ce, pcL + b*8192 + tr*512);
      async16(pa + (size_t)(t0+row)*BH + col0 + ce, paL + b*8192 + tr*512);
    }
    if (PH16){
#pragma unroll
      for (int j = 0; j < 2; ++j){
        const int tr  = wave*2 + j*8;
        const int row = tr + (lane >> 5);
        const int ce  = (lane & 31) * 8;
        async16(ph16 + (size_t)(t0+row)*BH + col0 + ce, phL + b*8192 + tr*512);
      }
    } else {
#pragma unroll
      for (int j = 0; j < 4; ++j){
        const int t = wave + j*4;
        async16(ph32 + (size_t)(t0+t)*BH + col0 + lane*4, phL + b*16384 + t*1024);
      }
    }
  };

  stage(0);
  asm volatile("s_waitcnt vmcnt(0)" ::: "memory");
  __builtin_amdgcn_s_barrier();
  __builtin_amdgcn_sched_barrier(0);

  constexpr int NC = T_SEQ / D_CH;
  for (int c = 0; c < NC; ++c){
    if (c + 1 < NC) stage(c + 1);
    const int b  = c & 1;
    const int t0 = c * D_CH;
    const unsigned short* pcb   = (const unsigned short*)(pcL + b*8192)  + tid;
    const unsigned short* pab   = (const unsigned short*)(paL + b*8192)  + tid;
    const unsigned short* phb16 = (const unsigned short*)(phL + b*8192)  + tid;
    const float*          phb32 = (const float*)(phL + b*16384) + tid;
#pragma unroll
    for (int i = 0; i < D_CH; ++i){
      float pcv = h2f(pcb[i*256]);
      float pav = h2f(pab[i*256]);
      float ph_ = PH16 ? h2f(phb16[i*256]) : phb32[i*256];
      float cc = sigm_f(pcv + wcv*h);
      float a  = 1.f + tanh_f(pav + wav*h);
      float hc = tanh_f(ph_ + a*h);
      h = cc*h + (1.f - cc)*hc;
      y[(size_t)(t0 + i)*BH + idx] = h;
    }
    if (c + 1 < NC){
      asm volatile("s_waitcnt vmcnt(16)" ::: "memory");
      __builtin_amdgcn_s_barrier();
      __builtin_amdgcn_sched_barrier(0);
    }
  }
  hlast[idx] = h;
}

extern "C" void kernel_launch(void* const* d_in, const int* in_sizes, int n_in,
                              void* d_out, int out_size, void* d_ws, size_t ws_size,
                              hipStream_t stream)
{
  const float* x  = (const float*)d_in[0];
  const float* h0 = (const float*)d_in[1];
  const float* Uc = (const float*)d_in[2];
  const float* wc = (const float*)d_in[3];
  const float* bc = (const float*)d_in[4];
  const float* Ua = (const float*)d_in[5];
  const float* wa = (const float*)d_in[6];
  const float* ba = (const float*)d_in[7];
  const float* Uh = (const float*)d_in[8];
  const float* bh = (const float*)d_in[9];

  float* y     = (float*)d_out;                 // [T,B,H]
  float* hlast = y + (size_t)T_SEQ * BH;        // [B,H]

  const size_t szP16 = (size_t)T_SEQ * BH * 2;     // 67,108,864 B
  const size_t szX16 = (size_t)M_TOT * IN_SZ * 2;  // 33,554,432 B
  const size_t szU16 = (size_t)HID * IN_SZ * 2;    // 1,048,576 B

  const size_t base = 2*szP16 + szX16 + 3*szU16;
  const bool ph_sep = ws_size >= base + szP16;     // separate fp16 ph buffer?

  char* w = (char*)d_ws;
  unsigned short* pc16 = (unsigned short*)w;
  unsigned short* pa16 = (unsigned short*)(w + szP16);
  unsigned short* xb   = (unsigned short*)(w + 2*szP16);
  unsigned short* U0b  = (unsigned short*)(w + 2*szP16 + szX16);
  unsigned short* U1b  = U0b + szU16/2;
  unsigned short* U2b  = U1b + szU16/2;
  unsigned short* ph16 = (unsigned short*)(w + base);   // only if ph_sep

  cvt_all<<<XBLK + 3*512, 256, 0, stream>>>(x, Uc, Ua, Uh, xb, U0b, U1b, U2b);

  void* phbuf = ph_sep ? (void*)ph16 : (void*)y;
  gemm3<<<512, 512, 0, stream>>>(xb, U0b, bc, (void*)pc16, 0);
  gemm3<<<512, 512, 0, stream>>>(xb, U1b, ba, (void*)pa16, 0);
  gemm3<<<512, 512, 0, stream>>>(xb, U2b, bh, phbuf, ph_sep ? 0 : 1);

  if (ph_sep)
    scan_k<true><<<BH/256, 256, 0, stream>>>(pc16, pa16, (const void*)ph16,
                                             y, h0, wc, wa, hlast);
  else
    scan_k<false><<<BH/256, 256, 0, stream>>>(pc16, pa16, (const void*)y,
                                              y, h0, wc, wa, hlast);
}

// Round 8
// 397.869 us; speedup vs baseline: 1.1592x; 1.0077x over previous
//
#include <hip/hip_runtime.h>
#include <cstdint>
#include <cstddef>

#define T_SEQ 512
#define BATCH 64
#define IN_SZ 512
#define HID   1024
#define BH    (BATCH*HID)      /* 65536 */
#define M_TOT (T_SEQ*BATCH)    /* 32768 */
#define D_CH  16               /* scan chunk depth */

typedef float f32x4 __attribute__((ext_vector_type(4)));
typedef _Float16 f16x8 __attribute__((ext_vector_type(8)));

__device__ inline unsigned short f2h(float f){
  union { _Float16 h; unsigned short u; } v;
  v.h = (_Float16)f;            // RTNE
  return v.u;
}
__device__ inline float h2f(unsigned short s){
  union { unsigned short u; _Float16 h; } v; v.u = s;
  return (float)v.h;
}

__device__ inline float sigm_f(float x){ return 1.f/(1.f + __expf(-x)); }
__device__ inline float tanh_f(float x){ float e = __expf(2.f*x); return 1.f - 2.f/(e + 1.f); }

// async global->LDS, 16B per lane; lds base must be wave-uniform
__device__ inline void async16(const void* g, void* l){
  __builtin_amdgcn_global_load_lds(
      (__attribute__((address_space(1))) void*)g,
      (__attribute__((address_space(3))) void*)l,
      16, 0, 0);
}

// ---------- fp32 -> fp16 conversion, v3: branch-free strided loops ----------
// r2 version (17,920 one-float4 blocks) ran at ~1.4 TB/s (budget analysis r7);
// r4's grid-stride test was confounded by per-element branchy pointer selection.
// v3: 1536 blocks; blocks 0..1023 convert x with 16 fixed-stride iterations
// (16 independent loads in flight/thread, zero branches); blocks 1024..1535
// convert the three U's with compile-time pointer selection (3 unrolled steps).
__global__ __launch_bounds__(256) void cvt_all(
    const float* __restrict__ x,  const float* __restrict__ Uc,
    const float* __restrict__ Ua, const float* __restrict__ Uh,
    unsigned short* __restrict__ xb, unsigned short* __restrict__ U0,
    unsigned short* __restrict__ U1, unsigned short* __restrict__ U2)
{
  const int b = blockIdx.x, t = threadIdx.x;
  if (b < 1024){
    const int i0 = b*256 + t;                 // stride 262144 float4
#pragma unroll
    for (int k = 0; k < 16; ++k){
      const int i = i0 + k*262144;
      float4 v = ((const float4*)x)[i];
      ushort4 o;
      o.x = f2h(v.x); o.y = f2h(v.y); o.z = f2h(v.z); o.w = f2h(v.w);
      ((ushort4*)xb)[i] = o;
    }
  } else {
    const int i = (b - 1024)*256 + t;         // 0..131071 (one full U each step)
    {
      float4 v = ((const float4*)Uc)[i];
      ushort4 o; o.x=f2h(v.x); o.y=f2h(v.y); o.z=f2h(v.z); o.w=f2h(v.w);
      ((ushort4*)U0)[i] = o;
    }
    {
      float4 v = ((const float4*)Ua)[i];
      ushort4 o; o.x=f2h(v.x); o.y=f2h(v.y); o.z=f2h(v.z); o.w=f2h(v.w);
      ((ushort4*)U1)[i] = o;
    }
    {
      float4 v = ((const float4*)Uh)[i];
      ushort4 o; o.x=f2h(v.x); o.y=f2h(v.y); o.z=f2h(v.z); o.w=f2h(v.w);
      ((ushort4*)U2)[i] = o;
    }
  }
}

// ---------- fused 3-projection GEMM: 256x256 tile, BK=64, 8 waves, phase-interleaved ----
// (byte-identical to verified round-2 version; 126 us, MfmaUtil ~35%)
__global__ __launch_bounds__(512, 2) void gemm3(
    const unsigned short* __restrict__ xb,
    const unsigned short* __restrict__ U0,
    const unsigned short* __restrict__ U1,
    const unsigned short* __restrict__ U2,
    const float* __restrict__ b0, const float* __restrict__ b1, const float* __restrict__ b2,
    unsigned short* out0, unsigned short* out1, void* out2, int ph_f16)
{
  __shared__ __align__(16) unsigned char smem_raw[131072];

  const int tid  = threadIdx.x;
  const int wave = tid >> 6, lane = tid & 63;
  const int quad = lane >> 4, l16 = lane & 15;

  const int bid  = blockIdx.x;          // 0..1535
  const int xcd  = bid & 7;
  const int slot = bid >> 3;            // 0..191
  const int mbl  = slot / 12;           // 0..15
  const int inner= slot - mbl*12;       // 0..11
  const int mb   = xcd*16 + mbl;        // 0..127
  const int z    = inner % 3;
  const int nb   = inner / 3;           // 0..3

  const int m0 = mb * 256, n0 = nb * 256;
  const unsigned short* Um = (z==0) ? U0 : (z==1) ? U1 : U2;
  const float* bias        = (z==0) ? b0 : (z==1) ? b1 : b2;
  const int wm = wave >> 2, wn = wave & 3;   // 2 x 4 wave grid; per-wave 128x64

  const int laneRow = lane >> 2;
  const int cg8     = ((lane & 3) ^ ((lane >> 3) & 3)) << 3;
  const unsigned short* srcA = xb + (size_t)m0 * IN_SZ;
  const unsigned short* srcB = Um + (size_t)n0 * IN_SZ;

  const int cxa = l16*64 + ((quad ^ ((l16 >> 1) & 3)) << 4);

  auto stageA = [&](int tile, int kh){
    unsigned char* dst = smem_raw + (((tile & 1)*2 + kh) << 14);
#pragma unroll
    for (int j = 0; j < 2; ++j){
      const unsigned short* g = srcA + (size_t)((wave*2 + j)*16 + laneRow)*IN_SZ
                                + tile*64 + kh*32 + cg8;
      async16(g, dst + (wave*2 + j)*1024);
    }
  };
  auto stageB = [&](int tile, int kh){
    unsigned char* dst = smem_raw + 65536 + (((tile & 1)*2 + kh) << 14);
#pragma unroll
    for (int j = 0; j < 2; ++j){
      const unsigned short* g = srcB + (size_t)((wave*2 + j)*16 + laneRow)*IN_SZ
                                + tile*64 + kh*32 + cg8;
      async16(g, dst + (wave*2 + j)*1024);
    }
  };

  const f32x4 zf = {0.f, 0.f, 0.f, 0.f};
  f32x4 acc[8][4];
#pragma unroll
  for (int i = 0; i < 8; ++i)
#pragma unroll
    for (int j = 0; j < 4; ++j) acc[i][j] = zf;

  stageA(0,0); stageB(0,0); stageA(0,1); stageB(0,1);
  stageA(1,0); stageB(1,0); stageA(1,1);
  asm volatile("s_waitcnt vmcnt(10)" ::: "memory");
  __builtin_amdgcn_s_barrier();

#define CLUSTER(B0_, B1_, N0_, N1_)                                                      \
  __builtin_amdgcn_s_barrier();                                                          \
  asm volatile("s_waitcnt lgkmcnt(0)" ::: "memory");                                     \
  __builtin_amdgcn_s_setprio(1);                                                         \
  _Pragma("unroll")                                                                      \
  for (int im_ = 0; im_ < 8; ++im_){                                                     \
    acc[im_][N0_] = __builtin_amdgcn_mfma_f32_16x16x32_f16(a0[im_], B0_, acc[im_][N0_], 0,0,0); \
    acc[im_][N1_] = __builtin_amdgcn_mfma_f32_16x16x32_f16(a0[im_], B1_, acc[im_][N1_], 0,0,0); \
  }                                                                                      \
  __builtin_amdgcn_s_setprio(0);                                                         \
  __builtin_amdgcn_s_barrier();

  f16x8 a0[8];
#pragma unroll
  for (int g = 0; g < 8; ++g){
    const int buf = g & 1;
    const unsigned char* Ab0 = smem_raw + ((buf*2 + 0) << 14);
    const unsigned char* Ab1 = smem_raw + ((buf*2 + 1) << 14);
    const unsigned char* Bb0 = smem_raw + 65536 + ((buf*2 + 0) << 14);
    const unsigned char* Bb1 = smem_raw + 65536 + ((buf*2 + 1) << 14);

    // ---- p1: ks0, n-frags 0,1
#pragma unroll
    for (int im = 0; im < 8; ++im)
      a0[im] = *(const f16x8*)(Ab0 + wm*8192 + im*1024 + cxa);
    f16x8 q0 = *(const f16x8*)(Bb0 + wn*4096 + 0*1024 + cxa);
    f16x8 q1 = *(const f16x8*)(Bb0 + wn*4096 + 1*1024 + cxa);
    if (g < 7) stageB(g+1, 1);
    CLUSTER(q0, q1, 0, 1)

    // ---- p2: ks0, n-frags 2,3
    f16x8 q2 = *(const f16x8*)(Bb0 + wn*4096 + 2*1024 + cxa);
    f16x8 q3 = *(const f16x8*)(Bb0 + wn*4096 + 3*1024 + cxa);
    if (g < 6) stageA(g+2, 0);
    if (g < 6)      { asm volatile("s_waitcnt vmcnt(10)" ::: "memory"); }
    else if (g == 6){ asm volatile("s_waitcnt vmcnt(8)"  ::: "memory"); }
    else            { asm volatile("s_waitcnt vmcnt(0)"  ::: "memory"); }
    CLUSTER(q2, q3, 2, 3)

    // ---- p3: ks1, n-frags 0,1
#pragma unroll
    for (int im = 0; im < 8; ++im)
      a0[im] = *(const f16x8*)(Ab1 + wm*8192 + im*1024 + cxa);
    q0 = *(const f16x8*)(Bb1 + wn*4096 + 0*1024 + cxa);
    q1 = *(const f16x8*)(Bb1 + wn*4096 + 1*1024 + cxa);
    if (g < 6) stageB(g+2, 0);
    CLUSTER(q0, q1, 0, 1)

    // ---- p4: ks1, n-frags 2,3
    q2 = *(const f16x8*)(Bb1 + wn*4096 + 2*1024 + cxa);
    q3 = *(const f16x8*)(Bb1 + wn*4096 + 3*1024 + cxa);
    if (g < 6) stageA(g+2, 1);
    if (g < 6)      { asm volatile("s_waitcnt vmcnt(10)" ::: "memory"); }
    else if (g == 6){ asm volatile("s_waitcnt vmcnt(4)"  ::: "memory"); }
    CLUSTER(q2, q3, 2, 3)
  }
#undef CLUSTER

  float bv[4];
#pragma unroll
  for (int in = 0; in < 4; ++in) bv[in] = bias[n0 + wn*64 + in*16 + l16];

  if (z == 2 && !ph_f16) {
    float* o32 = (float*)out2;
#pragma unroll
    for (int im = 0; im < 8; ++im)
#pragma unroll
      for (int r = 0; r < 4; ++r){
        int grow = m0 + wm*128 + im*16 + quad*4 + r;
        size_t rb = (size_t)grow * HID;
#pragma unroll
        for (int in = 0; in < 4; ++in)
          o32[rb + n0 + wn*64 + in*16 + l16] = acc[im][in][r] + bv[in];
      }
    return;
  }

  unsigned short* op = (z==0) ? out0 : (z==1) ? out1 : (unsigned short*)out2;
  unsigned short* sw = (unsigned short*)smem_raw + wave*4608;
#pragma unroll
  for (int h = 0; h < 2; ++h){
#pragma unroll
    for (int i4 = 0; i4 < 4; ++i4){
      int im = h*4 + i4;
#pragma unroll
      for (int r = 0; r < 4; ++r){
        int lr = i4*16 + quad*4 + r;
#pragma unroll
        for (int in = 0; in < 4; ++in)
          sw[lr*72 + in*16 + l16] = f2h(acc[im][in][r] + bv[in]);
      }
    }
    asm volatile("s_waitcnt lgkmcnt(0)" ::: "memory");
#pragma unroll
    for (int i = 0; i < 8; ++i){
      int lr = i*8 + (lane >> 3);
      int ch = lane & 7;
      uint4 v = *(const uint4*)(sw + lr*72 + ch*8);
      int grow = m0 + wm*128 + h*64 + lr;
      *(uint4*)(op + (size_t)grow*HID + n0 + wn*64 + ch*8) = v;
    }
    if (h == 0) asm volatile("s_waitcnt lgkmcnt(0)" ::: "memory");
  }
}

// ---------- elementwise recurrence, v2: block-cooperative LDS staging ----------
// (byte-identical to verified round-2/round-7 version; measured 89us, 0 conflicts)
template <bool PH16>
__global__ __launch_bounds__(256) void scan_k(
    const unsigned short* __restrict__ pc, const unsigned short* __restrict__ pa,
    const void* __restrict__ phv,
    float* __restrict__ y,
    const float* __restrict__ h0, const float* __restrict__ wc, const float* __restrict__ wa,
    float* __restrict__ hlast)
{
  __shared__ __align__(16) unsigned char sm[65536];
  const int tid  = threadIdx.x;
  const int wave = tid >> 6, lane = tid & 63;
  const int col0 = blockIdx.x * 256;
  const int idx  = col0 + tid;
  const int hidx = idx & (HID - 1);

  float h = h0[idx];
  const float wcv = wc[hidx], wav = wa[hidx];
  const unsigned short* ph16 = (const unsigned short*)phv;
  const float*          ph32 = (const float*)phv;

  unsigned char* pcL = sm;
  unsigned char* paL = sm + 16384;
  unsigned char* phL = sm + 32768;

  auto stage = [&](int c){
    const int b  = c & 1;
    const int t0 = c * D_CH;
#pragma unroll
    for (int j = 0; j < 2; ++j){
      const int tr  = wave*2 + j*8;
      const int row = tr + (lane >> 5);
      const int ce  = (lane & 31) * 8;
      async16(pc + (size_t)(t0+row)*BH + col0 + ce, pcL + b*8192 + tr*512);
      async16(pa + (size_t)(t0+row)*BH + col0 + ce, paL + b*8192 + tr*512);
    }
    if (PH16){
#pragma unroll
      for (int j = 0; j < 2; ++j){
        const int tr  = wave*2 + j*8;
        const int row = tr + (lane >> 5);
        const int ce  = (lane & 31) * 8;
        async16(ph16 + (size_t)(t0+row)*BH + col0 + ce, phL + b*8192 + tr*512);
      }
    } else {
#pragma unroll
      for (int j = 0; j < 4; ++j){
        const int t = wave + j*4;
        async16(ph32 + (size_t)(t0+t)*BH + col0 + lane*4, phL + b*16384 + t*1024);
      }
    }
  };

  stage(0);
  asm volatile("s_waitcnt vmcnt(0)" ::: "memory");
  __builtin_amdgcn_s_barrier();
  __builtin_amdgcn_sched_barrier(0);

  constexpr int NC = T_SEQ / D_CH;
  for (int c = 0; c < NC; ++c){
    if (c + 1 < NC) stage(c + 1);
    const int b  = c & 1;
    const int t0 = c * D_CH;
    const unsigned short* pcb   = (const unsigned short*)(pcL + b*8192)  + tid;
    const unsigned short* pab   = (const unsigned short*)(paL + b*8192)  + tid;
    const unsigned short* phb16 = (const unsigned short*)(phL + b*8192)  + tid;
    const float*          phb32 = (const float*)(phL + b*16384) + tid;
#pragma unroll
    for (int i = 0; i < D_CH; ++i){
      float pcv = h2f(pcb[i*256]);
      float pav = h2f(pab[i*256]);
      float ph_ = PH16 ? h2f(phb16[i*256]) : phb32[i*256];
      float cc = sigm_f(pcv + wcv*h);
      float a  = 1.f + tanh_f(pav + wav*h);
      float hc = tanh_f(ph_ + a*h);
      h = cc*h + (1.f - cc)*hc;
      y[(size_t)(t0 + i)*BH + idx] = h;
    }
    if (c + 1 < NC){
      asm volatile("s_waitcnt vmcnt(16)" ::: "memory");
      __builtin_amdgcn_s_barrier();
      __builtin_amdgcn_sched_barrier(0);
    }
  }
  hlast[idx] = h;
}

extern "C" void kernel_launch(void* const* d_in, const int* in_sizes, int n_in,
                              void* d_out, int out_size, void* d_ws, size_t ws_size,
                              hipStream_t stream)
{
  const float* x  = (const float*)d_in[0];
  const float* h0 = (const float*)d_in[1];
  const float* Uc = (const float*)d_in[2];
  const float* wc = (const float*)d_in[3];
  const float* bc = (const float*)d_in[4];
  const float* Ua = (const float*)d_in[5];
  const float* wa = (const float*)d_in[6];
  const float* ba = (const float*)d_in[7];
  const float* Uh = (const float*)d_in[8];
  const float* bh = (const float*)d_in[9];

  float* y     = (float*)d_out;                 // [T,B,H]
  float* hlast = y + (size_t)T_SEQ * BH;        // [B,H]

  const size_t szP16 = (size_t)T_SEQ * BH * 2;     // 67,108,864 B
  const size_t szX16 = (size_t)M_TOT * IN_SZ * 2;  // 33,554,432 B
  const size_t szU16 = (size_t)HID * IN_SZ * 2;    // 1,048,576 B

  const size_t base = 2*szP16 + szX16 + 3*szU16;
  const bool ph_sep = ws_size >= base + szP16;     // separate fp16 ph buffer?

  char* w = (char*)d_ws;
  unsigned short* pc16 = (unsigned short*)w;
  unsigned short* pa16 = (unsigned short*)(w + szP16);
  unsigned short* xb   = (unsigned short*)(w + 2*szP16);
  unsigned short* U0b  = (unsigned short*)(w + 2*szP16 + szX16);
  unsigned short* U1b  = U0b + szU16/2;
  unsigned short* U2b  = U1b + szU16/2;
  unsigned short* ph16 = (unsigned short*)(w + base);   // only if ph_sep

  cvt_all<<<1536, 256, 0, stream>>>(x, Uc, Ua, Uh, xb, U0b, U1b, U2b);

  void* phbuf = ph_sep ? (void*)ph16 : (void*)y;
  gemm3<<<1536, 512, 0, stream>>>(xb, U0b, U1b, U2b, bc, ba, bh,
                                  pc16, pa16, phbuf, ph_sep ? 1 : 0);

  if (ph_sep)
    scan_k<true><<<BH/256, 256, 0, stream>>>(pc16, pa16, (const void*)ph16,
                                             y, h0, wc, wa, hlast);
  else
    scan_k<false><<<BH/256, 256, 0, stream>>>(pc16, pa16, (const void*)y,
                                              y, h0, wc, wa, hlast);
}

// Round 9
// 372.884 us; speedup vs baseline: 1.2369x; 1.0670x over previous
//
#include <hip/hip_runtime.h>
#include <cstdint>
#include <cstddef>

#define T_SEQ 512
#define BATCH 64
#define IN_SZ 512
#define HID   1024
#define BH    (BATCH*HID)      /* 65536 */
#define M_TOT (T_SEQ*BATCH)    /* 32768 */
#define D_CH  16               /* scan chunk depth */

typedef float f32x4 __attribute__((ext_vector_type(4)));
typedef _Float16 f16x8 __attribute__((ext_vector_type(8)));

__device__ inline unsigned short f2h(float f){
  union { _Float16 h; unsigned short u; } v;
  v.h = (_Float16)f;            // RTNE
  return v.u;
}
__device__ inline float h2f(unsigned short s){
  union { unsigned short u; _Float16 h; } v; v.u = s;
  return (float)v.h;
}

__device__ inline float sigm_f(float x){ return 1.f/(1.f + __expf(-x)); }
__device__ inline float tanh_f(float x){ float e = __expf(2.f*x); return 1.f - 2.f/(e + 1.f); }

// async global->LDS, 16B per lane; lds base must be wave-uniform
__device__ inline void async16(const void* g, void* l){
  __builtin_amdgcn_global_load_lds(
      (__attribute__((address_space(1))) void*)g,
      (__attribute__((address_space(3))) void*)l,
      16, 0, 0);
}

// ---------- fp32 -> fp16 conversion, v3: branch-free strided loops ----------
// (byte-identical to round-8 version)
__global__ __launch_bounds__(256) void cvt_all(
    const float* __restrict__ x,  const float* __restrict__ Uc,
    const float* __restrict__ Ua, const float* __restrict__ Uh,
    unsigned short* __restrict__ xb, unsigned short* __restrict__ U0,
    unsigned short* __restrict__ U1, unsigned short* __restrict__ U2)
{
  const int b = blockIdx.x, t = threadIdx.x;
  if (b < 1024){
    const int i0 = b*256 + t;                 // stride 262144 float4
#pragma unroll
    for (int k = 0; k < 16; ++k){
      const int i = i0 + k*262144;
      float4 v = ((const float4*)x)[i];
      ushort4 o;
      o.x = f2h(v.x); o.y = f2h(v.y); o.z = f2h(v.z); o.w = f2h(v.w);
      ((ushort4*)xb)[i] = o;
    }
  } else {
    const int i = (b - 1024)*256 + t;         // 0..131071 (one full U each step)
    {
      float4 v = ((const float4*)Uc)[i];
      ushort4 o; o.x=f2h(v.x); o.y=f2h(v.y); o.z=f2h(v.z); o.w=f2h(v.w);
      ((ushort4*)U0)[i] = o;
    }
    {
      float4 v = ((const float4*)Ua)[i];
      ushort4 o; o.x=f2h(v.x); o.y=f2h(v.y); o.z=f2h(v.z); o.w=f2h(v.w);
      ((ushort4*)U1)[i] = o;
    }
    {
      float4 v = ((const float4*)Uh)[i];
      ushort4 o; o.x=f2h(v.x); o.y=f2h(v.y); o.z=f2h(v.z); o.w=f2h(v.w);
      ((ushort4*)U2)[i] = o;
    }
  }
}

// ---------- fused 3-projection GEMM: 256x256 tile, BK=64, 8 waves, phase-interleaved ----
// (byte-identical to verified round-2 version; 126-133 us by run clock, MfmaUtil ~35%)
__global__ __launch_bounds__(512, 2) void gemm3(
    const unsigned short* __restrict__ xb,
    const unsigned short* __restrict__ U0,
    const unsigned short* __restrict__ U1,
    const unsigned short* __restrict__ U2,
    const float* __restrict__ b0, const float* __restrict__ b1, const float* __restrict__ b2,
    unsigned short* out0, unsigned short* out1, void* out2, int ph_f16)
{
  __shared__ __align__(16) unsigned char smem_raw[131072];

  const int tid  = threadIdx.x;
  const int wave = tid >> 6, lane = tid & 63;
  const int quad = lane >> 4, l16 = lane & 15;

  const int bid  = blockIdx.x;          // 0..1535
  const int xcd  = bid & 7;
  const int slot = bid >> 3;            // 0..191
  const int mbl  = slot / 12;           // 0..15
  const int inner= slot - mbl*12;       // 0..11
  const int mb   = xcd*16 + mbl;        // 0..127
  const int z    = inner % 3;
  const int nb   = inner / 3;           // 0..3

  const int m0 = mb * 256, n0 = nb * 256;
  const unsigned short* Um = (z==0) ? U0 : (z==1) ? U1 : U2;
  const float* bias        = (z==0) ? b0 : (z==1) ? b1 : b2;
  const int wm = wave >> 2, wn = wave & 3;   // 2 x 4 wave grid; per-wave 128x64

  const int laneRow = lane >> 2;
  const int cg8     = ((lane & 3) ^ ((lane >> 3) & 3)) << 3;
  const unsigned short* srcA = xb + (size_t)m0 * IN_SZ;
  const unsigned short* srcB = Um + (size_t)n0 * IN_SZ;

  const int cxa = l16*64 + ((quad ^ ((l16 >> 1) & 3)) << 4);

  auto stageA = [&](int tile, int kh){
    unsigned char* dst = smem_raw + (((tile & 1)*2 + kh) << 14);
#pragma unroll
    for (int j = 0; j < 2; ++j){
      const unsigned short* g = srcA + (size_t)((wave*2 + j)*16 + laneRow)*IN_SZ
                                + tile*64 + kh*32 + cg8;
      async16(g, dst + (wave*2 + j)*1024);
    }
  };
  auto stageB = [&](int tile, int kh){
    unsigned char* dst = smem_raw + 65536 + (((tile & 1)*2 + kh) << 14);
#pragma unroll
    for (int j = 0; j < 2; ++j){
      const unsigned short* g = srcB + (size_t)((wave*2 + j)*16 + laneRow)*IN_SZ
                                + tile*64 + kh*32 + cg8;
      async16(g, dst + (wave*2 + j)*1024);
    }
  };

  const f32x4 zf = {0.f, 0.f, 0.f, 0.f};
  f32x4 acc[8][4];
#pragma unroll
  for (int i = 0; i < 8; ++i)
#pragma unroll
    for (int j = 0; j < 4; ++j) acc[i][j] = zf;

  stageA(0,0); stageB(0,0); stageA(0,1); stageB(0,1);
  stageA(1,0); stageB(1,0); stageA(1,1);
  asm volatile("s_waitcnt vmcnt(10)" ::: "memory");
  __builtin_amdgcn_s_barrier();

#define CLUSTER(B0_, B1_, N0_, N1_)                                                      \
  __builtin_amdgcn_s_barrier();                                                          \
  asm volatile("s_waitcnt lgkmcnt(0)" ::: "memory");                                     \
  __builtin_amdgcn_s_setprio(1);                                                         \
  _Pragma("unroll")                                                                      \
  for (int im_ = 0; im_ < 8; ++im_){                                                     \
    acc[im_][N0_] = __builtin_amdgcn_mfma_f32_16x16x32_f16(a0[im_], B0_, acc[im_][N0_], 0,0,0); \
    acc[im_][N1_] = __builtin_amdgcn_mfma_f32_16x16x32_f16(a0[im_], B1_, acc[im_][N1_], 0,0,0); \
  }                                                                                      \
  __builtin_amdgcn_s_setprio(0);                                                         \
  __builtin_amdgcn_s_barrier();

  f16x8 a0[8];
#pragma unroll
  for (int g = 0; g < 8; ++g){
    const int buf = g & 1;
    const unsigned char* Ab0 = smem_raw + ((buf*2 + 0) << 14);
    const unsigned char* Ab1 = smem_raw + ((buf*2 + 1) << 14);
    const unsigned char* Bb0 = smem_raw + 65536 + ((buf*2 + 0) << 14);
    const unsigned char* Bb1 = smem_raw + 65536 + ((buf*2 + 1) << 14);

    // ---- p1: ks0, n-frags 0,1
#pragma unroll
    for (int im = 0; im < 8; ++im)
      a0[im] = *(const f16x8*)(Ab0 + wm*8192 + im*1024 + cxa);
    f16x8 q0 = *(const f16x8*)(Bb0 + wn*4096 + 0*1024 + cxa);
    f16x8 q1 = *(const f16x8*)(Bb0 + wn*4096 + 1*1024 + cxa);
    if (g < 7) stageB(g+1, 1);
    CLUSTER(q0, q1, 0, 1)

    // ---- p2: ks0, n-frags 2,3
    f16x8 q2 = *(const f16x8*)(Bb0 + wn*4096 + 2*1024 + cxa);
    f16x8 q3 = *(const f16x8*)(Bb0 + wn*4096 + 3*1024 + cxa);
    if (g < 6) stageA(g+2, 0);
    if (g < 6)      { asm volatile("s_waitcnt vmcnt(10)" ::: "memory"); }
    else if (g == 6){ asm volatile("s_waitcnt vmcnt(8)"  ::: "memory"); }
    else            { asm volatile("s_waitcnt vmcnt(0)"  ::: "memory"); }
    CLUSTER(q2, q3, 2, 3)

    // ---- p3: ks1, n-frags 0,1
#pragma unroll
    for (int im = 0; im < 8; ++im)
      a0[im] = *(const f16x8*)(Ab1 + wm*8192 + im*1024 + cxa);
    q0 = *(const f16x8*)(Bb1 + wn*4096 + 0*1024 + cxa);
    q1 = *(const f16x8*)(Bb1 + wn*4096 + 1*1024 + cxa);
    if (g < 6) stageB(g+2, 0);
    CLUSTER(q0, q1, 0, 1)

    // ---- p4: ks1, n-frags 2,3
    q2 = *(const f16x8*)(Bb1 + wn*4096 + 2*1024 + cxa);
    q3 = *(const f16x8*)(Bb1 + wn*4096 + 3*1024 + cxa);
    if (g < 6) stageA(g+2, 1);
    if (g < 6)      { asm volatile("s_waitcnt vmcnt(10)" ::: "memory"); }
    else if (g == 6){ asm volatile("s_waitcnt vmcnt(4)"  ::: "memory"); }
    CLUSTER(q2, q3, 2, 3)
  }
#undef CLUSTER

  float bv[4];
#pragma unroll
  for (int in = 0; in < 4; ++in) bv[in] = bias[n0 + wn*64 + in*16 + l16];

  if (z == 2 && !ph_f16) {
    float* o32 = (float*)out2;
#pragma unroll
    for (int im = 0; im < 8; ++im)
#pragma unroll
      for (int r = 0; r < 4; ++r){
        int grow = m0 + wm*128 + im*16 + quad*4 + r;
        size_t rb = (size_t)grow * HID;
#pragma unroll
        for (int in = 0; in < 4; ++in)
          o32[rb + n0 + wn*64 + in*16 + l16] = acc[im][in][r] + bv[in];
      }
    return;
  }

  unsigned short* op = (z==0) ? out0 : (z==1) ? out1 : (unsigned short*)out2;
  unsigned short* sw = (unsigned short*)smem_raw + wave*4608;
#pragma unroll
  for (int h = 0; h < 2; ++h){
#pragma unroll
    for (int i4 = 0; i4 < 4; ++i4){
      int im = h*4 + i4;
#pragma unroll
      for (int r = 0; r < 4; ++r){
        int lr = i4*16 + quad*4 + r;
#pragma unroll
        for (int in = 0; in < 4; ++in)
          sw[lr*72 + in*16 + l16] = f2h(acc[im][in][r] + bv[in]);
      }
    }
    asm volatile("s_waitcnt lgkmcnt(0)" ::: "memory");
#pragma unroll
    for (int i = 0; i < 8; ++i){
      int lr = i*8 + (lane >> 3);
      int ch = lane & 7;
      uint4 v = *(const uint4*)(sw + lr*72 + ch*8);
      int grow = m0 + wm*128 + h*64 + lr;
      *(uint4*)(op + (size_t)grow*HID + n0 + wn*64 + ch*8) = v;
    }
    if (h == 0) asm volatile("s_waitcnt lgkmcnt(0)" ::: "memory");
  }
}

// ---------- elementwise recurrence, v4: WAVE-PRIVATE barrier-free staging ----------
// r7 measured the v2 block-cooperative version at 89us (58% VALU, 2.65 TB/s) with
// 32 block-wide s_barriers at 1 wave/SIMD: every chunk pays the slowest wave's
// memory service and no wave can drift to hide HBM latency. v4: each wave stages
// only its own 64 columns (6 async16/chunk; lane -> row=l>>3, col=(l&7)*8 covers
// 8 t-rows x 64 cols per issue; LDS read telescopes to buf*2048 + i*128 + lane*2,
// 2 lanes/bank = conflict-free), per-wave counted vmcnt, ZERO barriers.
// vmcnt ledger (per wave, PH16): queue = loads(c)[6], stores(c-1)[16], loads(c+1)[6].
//   c=0: wait 6; steady: wait 22 (retires loads(c), keeps stores+next loads);
//   tail c=NC-1: wait 16. PH32: 8 loads/stage -> 8 / 24 / 16.
template <bool PH16>
__global__ __launch_bounds__(256) void scan_k(
    const unsigned short* __restrict__ pc, const unsigned short* __restrict__ pa,
    const void* __restrict__ phv,
    float* __restrict__ y,
    const float* __restrict__ h0, const float* __restrict__ wc, const float* __restrict__ wa,
    float* __restrict__ hlast)
{
  __shared__ __align__(16) unsigned char sm[65536];   // 4 waves x 16KB regions
  const int tid  = threadIdx.x;
  const int wave = tid >> 6, lane = tid & 63;
  const int col0 = blockIdx.x * 256;
  const int idx  = col0 + tid;
  const int hidx = idx & (HID - 1);

  float h = h0[idx];
  const float wcv = wc[hidx], wav = wa[hidx];
  const unsigned short* ph16 = (const unsigned short*)phv;
  const float*          ph32 = (const float*)phv;

  // wave-private region: pc [2][2KB] @0, pa [2][2KB] @4K, ph @8K ([2][2KB] f16 / [2][4KB] f32)
  unsigned char* wr  = sm + wave*16384;
  unsigned char* pcW = wr;
  unsigned char* paW = wr + 4096;
  unsigned char* phW = wr + 8192;

  const int colW = col0 + wave*64;          // this wave's 64-column slice
  const int r8   = lane >> 3;               // u16 staging: row within 8-row group
  const int c8   = (lane & 7) * 8;          // u16 staging: ushort col offset
  const int r4   = lane >> 4;               // f32 staging: row within 4-row group
  const int c4   = (lane & 15) * 4;         // f32 staging: float col offset

  auto stage = [&](int c){
    const int b  = c & 1;
    const int t0 = c * D_CH;
#pragma unroll
    for (int j = 0; j < 2; ++j){
      const int row = t0 + j*8 + r8;
      async16(pc + (size_t)row*BH + colW + c8, pcW + b*2048 + j*1024);
      async16(pa + (size_t)row*BH + colW + c8, paW + b*2048 + j*1024);
    }
    if (PH16){
#pragma unroll
      for (int j = 0; j < 2; ++j){
        const int row = t0 + j*8 + r8;
        async16(ph16 + (size_t)row*BH + colW + c8, phW + b*2048 + j*1024);
      }
    } else {
#pragma unroll
      for (int j = 0; j < 4; ++j){
        const int row = t0 + j*4 + r4;
        async16(ph32 + (size_t)row*BH + colW + c4, phW + b*4096 + j*1024);
      }
    }
  };

  constexpr int NC = T_SEQ / D_CH;
  stage(0);
  for (int c = 0; c < NC; ++c){
    if (c + 1 < NC) stage(c + 1);
    // retire loads(c); never drain stores or next-chunk loads (per-wave counter)
    if (c == 0){
      if (PH16) asm volatile("s_waitcnt vmcnt(6)"  ::: "memory");
      else      asm volatile("s_waitcnt vmcnt(8)"  ::: "memory");
    } else if (c + 1 < NC){
      if (PH16) asm volatile("s_waitcnt vmcnt(22)" ::: "memory");
      else      asm volatile("s_waitcnt vmcnt(24)" ::: "memory");
    } else {
      asm volatile("s_waitcnt vmcnt(16)" ::: "memory");
    }
    __builtin_amdgcn_sched_barrier(0);       // rule #18: pin ds_reads behind the vmcnt

    const int b  = c & 1;
    const int t0 = c * D_CH;
    const unsigned char* pcb = pcW + b*2048 + lane*2;
    const unsigned char* pab = paW + b*2048 + lane*2;
    const unsigned char* phb = phW + (PH16 ? b*2048 + lane*2 : b*4096 + lane*4);
#pragma unroll
    for (int i = 0; i < D_CH; ++i){
      float pcv = h2f(*(const unsigned short*)(pcb + i*128));
      float pav = h2f(*(const unsigned short*)(pab + i*128));
      float ph_ = PH16 ? h2f(*(const unsigned short*)(phb + i*128))
                       : *(const float*)(phb + i*256);
      float cc = sigm_f(pcv + wcv*h);
      float a  = 1.f + tanh_f(pav + wav*h);
      float hc = tanh_f(ph_ + a*h);
      h = cc*h + (1.f - cc)*hc;
      y[(size_t)(t0 + i)*BH + idx] = h;
    }
  }
  hlast[idx] = h;
}

extern "C" void kernel_launch(void* const* d_in, const int* in_sizes, int n_in,
                              void* d_out, int out_size, void* d_ws, size_t ws_size,
                              hipStream_t stream)
{
  const float* x  = (const float*)d_in[0];
  const float* h0 = (const float*)d_in[1];
  const float* Uc = (const float*)d_in[2];
  const float* wc = (const float*)d_in[3];
  const float* bc = (const float*)d_in[4];
  const float* Ua = (const float*)d_in[5];
  const float* wa = (const float*)d_in[6];
  const float* ba = (const float*)d_in[7];
  const float* Uh = (const float*)d_in[8];
  const float* bh = (const float*)d_in[9];

  float* y     = (float*)d_out;                 // [T,B,H]
  float* hlast = y + (size_t)T_SEQ * BH;        // [B,H]

  const size_t szP16 = (size_t)T_SEQ * BH * 2;     // 67,108,864 B
  const size_t szX16 = (size_t)M_TOT * IN_SZ * 2;  // 33,554,432 B
  const size_t szU16 = (size_t)HID * IN_SZ * 2;    // 1,048,576 B

  const size_t base = 2*szP16 + szX16 + 3*szU16;
  const bool ph_sep = ws_size >= base + szP16;     // separate fp16 ph buffer?

  char* w = (char*)d_ws;
  unsigned short* pc16 = (unsigned short*)w;
  unsigned short* pa16 = (unsigned short*)(w + szP16);
  unsigned short* xb   = (unsigned short*)(w + 2*szP16);
  unsigned short* U0b  = (unsigned short*)(w + 2*szP16 + szX16);
  unsigned short* U1b  = U0b + szU16/2;
  unsigned short* U2b  = U1b + szU16/2;
  unsigned short* ph16 = (unsigned short*)(w + base);   // only if ph_sep

  cvt_all<<<1536, 256, 0, stream>>>(x, Uc, Ua, Uh, xb, U0b, U1b, U2b);

  void* phbuf = ph_sep ? (void*)ph16 : (void*)y;
  gemm3<<<1536, 512, 0, stream>>>(xb, U0b, U1b, U2b, bc, ba, bh,
                                  pc16, pa16, phbuf, ph_sep ? 1 : 0);

  if (ph_sep)
    scan_k<true><<<BH/256, 256, 0, stream>>>(pc16, pa16, (const void*)ph16,
                                             y, h0, wc, wa, hlast);
  else
    scan_k<false><<<BH/256, 256, 0, stream>>>(pc16, pa16, (const void*)y,
                                              y, h0, wc, wa, hlast);
}